// Round 1
// baseline (21517.245 us; speedup 1.0000x reference)
//
#include <hip/hip_runtime.h>
#include <hip/hip_bf16.h>
#include <cstdint>

#define B_   32
#define T_   500
#define H_   512
#define ENC_ 1024
#define V_   10000
#define L_   100
#define H4_  2048

// workspace layout (float offsets)
#define OFF_HPROJ 0
#define OFF_S     8192000
#define OFF_C     (OFF_S + 16384)
#define OFF_SWS   (OFF_C + 16384)
#define OFF_DACC  (OFF_SWS + 16384)
#define OFF_RACC  (OFF_DACC + 16384)
#define OFF_E     (OFF_RACC + 65536)
#define OFF_G     (OFF_E + 16000)
#define OFF_DECT  (OFF_G + 32768)
// total = 8388224 floats = 33.6 MB

__device__ __forceinline__ float ftanh(float x){
  float t = fminf(fmaxf(2.f*x, -30.f), 30.f);
  float e = __expf(t);
  return (e - 1.f) / (e + 1.f);
}
__device__ __forceinline__ float fsig(float x){
  float t = fminf(fmaxf(x, -30.f), 30.f);
  return 1.f / (1.f + __expf(-t));
}

// zero the state region: s, c, sws, dacc, racc (contiguous, 131072 floats)
__global__ void k_init(float* __restrict__ ws){
  int i = blockIdx.x * 256 + threadIdx.x;
  if (i < 131072) ws[OFF_S + i] = 0.f;
}

// h_proj[m, n] = sum_k h_batch[m,k] * Wh[k,n] + bias[n]; M=16000,K=1024,N=512
// skip blocks whose 64 rows are all masked (t >= seq_lens[b])
__global__ void k_hproj(const float* __restrict__ A, const float* __restrict__ W,
                        const float* __restrict__ bias, const int* __restrict__ lens,
                        float* __restrict__ C){
  const int bm = blockIdx.x * 64;
  const int bn = blockIdx.y * 64;
  {
    int b0 = bm / T_, t0 = bm % T_;
    int b1 = (bm + 63) / T_;
    if (b0 == b1 && t0 >= lens[b0]) return;   // fully masked tile
  }
  __shared__ float As[64][33];
  __shared__ float Bs[32][68];
  const int tid = threadIdx.x;
  const int tx = tid & 15, ty = tid >> 4;
  float acc[4][4];
  #pragma unroll
  for (int i = 0; i < 4; ++i)
    #pragma unroll
    for (int j = 0; j < 4; ++j) acc[i][j] = 0.f;

  for (int k0 = 0; k0 < 1024; k0 += 32){
    for (int i = tid; i < 64*32; i += 256){
      int r = i >> 5, cc = i & 31;
      As[r][cc] = A[(size_t)(bm + r) * 1024 + k0 + cc];
    }
    for (int i = tid; i < 32*64; i += 256){
      int r = i >> 6, cc = i & 63;
      Bs[r][cc] = W[(size_t)(k0 + r) * 512 + bn + cc];
    }
    __syncthreads();
    #pragma unroll
    for (int kk = 0; kk < 32; ++kk){
      float a0 = As[ty*4+0][kk], a1 = As[ty*4+1][kk];
      float a2 = As[ty*4+2][kk], a3 = As[ty*4+3][kk];
      float4 b4 = *(const float4*)&Bs[kk][tx*4];
      acc[0][0] += a0*b4.x; acc[0][1] += a0*b4.y; acc[0][2] += a0*b4.z; acc[0][3] += a0*b4.w;
      acc[1][0] += a1*b4.x; acc[1][1] += a1*b4.y; acc[1][2] += a1*b4.z; acc[1][3] += a1*b4.w;
      acc[2][0] += a2*b4.x; acc[2][1] += a2*b4.y; acc[2][2] += a2*b4.z; acc[2][3] += a2*b4.w;
      acc[3][0] += a3*b4.x; acc[3][1] += a3*b4.y; acc[3][2] += a3*b4.z; acc[3][3] += a3*b4.w;
    }
    __syncthreads();
  }
  #pragma unroll
  for (int i = 0; i < 4; ++i){
    int m = bm + ty*4 + i;
    float4 o;
    o.x = acc[i][0] + bias[bn + tx*4 + 0];
    o.y = acc[i][1] + bias[bn + tx*4 + 1];
    o.z = acc[i][2] + bias[bn + tx*4 + 2];
    o.w = acc[i][3] + bias[bn + tx*4 + 3];
    *(float4*)&C[(size_t)m * 512 + bn + tx*4] = o;
  }
}

// sws[b, col] += sum_k s[b,k] * Ws[k,col]   grid(2,8) block 256, k-chunk 64
__global__ void k_sws(const float* __restrict__ s, const float* __restrict__ Ws,
                      float* __restrict__ sws){
  const int col = blockIdx.x * 256 + threadIdx.x;
  const int k0  = blockIdx.y * 64;
  __shared__ __align__(16) float sb[32][64];
  for (int i = threadIdx.x; i < 32*64; i += 256){
    int bi = i >> 6, kk = i & 63;
    sb[bi][kk] = s[bi * H_ + k0 + kk];
  }
  __syncthreads();
  float acc[32];
  #pragma unroll
  for (int bi = 0; bi < 32; ++bi) acc[bi] = 0.f;
  for (int kk = 0; kk < 64; kk += 4){
    float w0 = Ws[(size_t)(k0+kk+0)*512 + col];
    float w1 = Ws[(size_t)(k0+kk+1)*512 + col];
    float w2 = Ws[(size_t)(k0+kk+2)*512 + col];
    float w3 = Ws[(size_t)(k0+kk+3)*512 + col];
    #pragma unroll
    for (int bi = 0; bi < 32; ++bi){
      float4 a = *(const float4*)&sb[bi][kk];
      acc[bi] += a.x*w0 + a.y*w1 + a.z*w2 + a.w*w3;
    }
  }
  #pragma unroll
  for (int bi = 0; bi < 32; ++bi)
    atomicAdd(&sws[bi * H_ + col], acc[bi]);
}

// e[b,t] = v . tanh(hproj[b,t,:] + sws[b,:])  (only t < len); one wave per row
__global__ void k_escore(const float* __restrict__ hproj, const float* __restrict__ sws,
                         const float* __restrict__ v, const int* __restrict__ lens,
                         float* __restrict__ e){
  const int row  = blockIdx.x * 4 + (threadIdx.x >> 6);
  const int lane = threadIdx.x & 63;
  const int b = row / T_, t = row - b * T_;
  if (t >= lens[b]) return;
  const float* hp = hproj + (size_t)row * H_;
  const float* sw = sws + b * H_;
  float sum = 0.f;
  #pragma unroll
  for (int it = 0; it < 2; ++it){
    int h = it*256 + lane*4;
    float4 a  = *(const float4*)&hp[h];
    float4 s4 = *(const float4*)&sw[h];
    float4 vv = *(const float4*)&v[h];
    sum += vv.x * ftanh(a.x + s4.x);
    sum += vv.y * ftanh(a.y + s4.y);
    sum += vv.z * ftanh(a.z + s4.z);
    sum += vv.w * ftanh(a.w + s4.w);
  }
  #pragma unroll
  for (int off = 32; off > 0; off >>= 1)
    sum += __shfl_xor(sum, off, 64);
  if (lane == 0) e[row] = sum;
}

// masked softmax over t (in LDS) + g[b,ec] = sum_t alpha[t]*h_batch[b,t,ec]
// grid (32 b, 4 ec-chunks) block 256
__global__ void k_attng(const float* __restrict__ e, const float* __restrict__ hb,
                        const int* __restrict__ lens, float* __restrict__ g){
  const int b   = blockIdx.x;
  const int ec  = blockIdx.y * 256 + threadIdx.x;
  const int tid = threadIdx.x;
  const int len = lens[b];
  __shared__ float sc[512];
  __shared__ float red[256];
  float lmax = -1e30f;
  for (int t = tid; t < T_; t += 256){
    float val = (t < len) ? e[b*T_ + t] : -1e30f;
    sc[t] = val;
    lmax = fmaxf(lmax, val);
  }
  red[tid] = lmax; __syncthreads();
  for (int st = 128; st > 0; st >>= 1){
    if (tid < st) red[tid] = fmaxf(red[tid], red[tid+st]);
    __syncthreads();
  }
  float mx = red[0]; __syncthreads();
  float lsum = 0.f;
  for (int t = tid; t < T_; t += 256){
    float ex = (t < len) ? __expf(sc[t] - mx) : 0.f;
    sc[t] = ex;
    lsum += ex;
  }
  red[tid] = lsum; __syncthreads();
  for (int st = 128; st > 0; st >>= 1){
    if (tid < st) red[tid] += red[tid+st];
    __syncthreads();
  }
  const float inv = 1.f / red[0];
  // barriers above ensure sc[] writes visible
  float acc = 0.f;
  const float* hbb = hb + (size_t)b * T_ * ENC_ + ec;
  int t = 0;
  for (; t + 4 <= len; t += 4){
    acc += sc[t]   * hbb[(size_t)(t)   * ENC_];
    acc += sc[t+1] * hbb[(size_t)(t+1) * ENC_];
    acc += sc[t+2] * hbb[(size_t)(t+2) * ENC_];
    acc += sc[t+3] * hbb[(size_t)(t+3) * ENC_];
  }
  for (; t < len; ++t) acc += sc[t] * hbb[(size_t)t * ENC_];
  g[b*ENC_ + ec] = acc * inv;
}

// dec/rec matmuls: cols 0..511 -> dacc (s@Wsy + g@Wgy), cols 512..2559 -> racc
// grid (10 colblk, 4 bgroups of 8, 2 k-chunks of 768) block 256
__global__ void k_recmm(const float* __restrict__ s, const float* __restrict__ g,
                        const float* __restrict__ Wsy, const float* __restrict__ Wgy,
                        const float* __restrict__ Wsr, const float* __restrict__ Wgr,
                        float* __restrict__ dacc, float* __restrict__ racc){
  const int col  = blockIdx.x * 256 + threadIdx.x;
  const int bset = blockIdx.y * 8;
  const int k0   = blockIdx.z * 768;
  __shared__ __align__(16) float act[8][768];
  for (int i = threadIdx.x; i < 8*768; i += 256){
    int bi = i / 768, kk = i - bi*768;
    int k = k0 + kk;
    act[bi][kk] = (k < 512) ? s[(bset+bi)*H_ + k] : g[(bset+bi)*ENC_ + (k - 512)];
  }
  __syncthreads();
  const bool isdec = (col < 512);
  const int cr = col - 512;
  float acc[8];
  #pragma unroll
  for (int bi = 0; bi < 8; ++bi) acc[bi] = 0.f;
  for (int kk = 0; kk < 768; kk += 4){
    float w[4];
    #pragma unroll
    for (int j = 0; j < 4; ++j){
      int k = k0 + kk + j;
      const float* wp;
      if (isdec) wp = (k < 512) ? &Wsy[(size_t)k*512 + col]  : &Wgy[(size_t)(k-512)*512 + col];
      else       wp = (k < 512) ? &Wsr[(size_t)k*2048 + cr]  : &Wgr[(size_t)(k-512)*2048 + cr];
      w[j] = *wp;
    }
    #pragma unroll
    for (int bi = 0; bi < 8; ++bi){
      float4 a = *(const float4*)&act[bi][kk];
      acc[bi] += a.x*w[0] + a.y*w[1] + a.z*w[2] + a.w*w[3];
    }
  }
  #pragma unroll
  for (int bi = 0; bi < 8; ++bi){
    if (isdec) atomicAdd(&dacc[(bset+bi)*H_  + col], acc[bi]);
    else       atomicAdd(&racc[(bset+bi)*H4_ + cr],  acc[bi]);
  }
}

// gates + LSTM update + dec_tanh; also zero accumulators/sws for next step
__global__ void k_lstm(float* __restrict__ dacc, float* __restrict__ racc,
                       float* __restrict__ s, float* __restrict__ c,
                       float* __restrict__ sws, float* __restrict__ dect,
                       const float* __restrict__ E_yr, const int* __restrict__ labels,
                       const float* __restrict__ b_sy, const float* __restrict__ b_gy,
                       const float* __restrict__ b_sr, const float* __restrict__ b_gr,
                       int l){
  const int b = blockIdx.x;
  const int h = threadIdx.x;      // 512 threads
  const int lab = labels[b*L_ + l];
  const float* ey = E_yr + (size_t)lab * H4_;
  float ri = racc[b*H4_ + h]          + b_sr[h]        + b_gr[h]        + ey[h];
  float rf = racc[b*H4_ + 512 + h]    + b_sr[512+h]    + b_gr[512+h]    + ey[512+h];
  float rg = racc[b*H4_ + 1024 + h]   + b_sr[1024+h]   + b_gr[1024+h]   + ey[1024+h];
  float ro = racc[b*H4_ + 1536 + h]   + b_sr[1536+h]   + b_gr[1536+h]   + ey[1536+h];
  float cold = c[b*H_ + h];
  float cn = fsig(rf)*cold + fsig(ri)*ftanh(rg);
  float sn = fsig(ro)*ftanh(cn);
  c[b*H_ + h] = cn;
  s[b*H_ + h] = sn;
  float d = dacc[b*H_ + h] + b_sy[h] + b_gy[h];
  dect[b*H_ + h] = ftanh(d);
  racc[b*H4_ + h] = 0.f; racc[b*H4_ + 512 + h] = 0.f;
  racc[b*H4_ + 1024 + h] = 0.f; racc[b*H4_ + 1536 + h] = 0.f;
  dacc[b*H_ + h] = 0.f;
  sws[b*H_ + h] = 0.f;
}

// y[b,v] = dect[b,:] @ Wyy[:,v] + byy[v] -> out[b,l,v]; grid (40 vblk, 4 bgroups) block 256
__global__ void k_vocab(const float* __restrict__ dect, const float* __restrict__ Wyy,
                        const float* __restrict__ byy, float* __restrict__ out, int l){
  const int v    = blockIdx.x * 256 + threadIdx.x;
  const int bset = blockIdx.y * 8;
  __shared__ __align__(16) float dt[8][512];
  for (int i = threadIdx.x; i < 8*512; i += 256){
    int bi = i >> 9, hh = i & 511;
    dt[bi][hh] = dect[(bset+bi)*H_ + hh];
  }
  __syncthreads();
  if (v >= V_) return;
  float acc[8];
  #pragma unroll
  for (int bi = 0; bi < 8; ++bi) acc[bi] = 0.f;
  for (int h = 0; h < 512; h += 4){
    float w0 = Wyy[(size_t)(h+0)*V_ + v];
    float w1 = Wyy[(size_t)(h+1)*V_ + v];
    float w2 = Wyy[(size_t)(h+2)*V_ + v];
    float w3 = Wyy[(size_t)(h+3)*V_ + v];
    #pragma unroll
    for (int bi = 0; bi < 8; ++bi){
      float4 a = *(const float4*)&dt[bi][h];
      acc[bi] += a.x*w0 + a.y*w1 + a.z*w2 + a.w*w3;
    }
  }
  const float bb = byy[v];
  #pragma unroll
  for (int bi = 0; bi < 8; ++bi)
    out[((size_t)(bset+bi)*L_ + l)*V_ + v] = acc[bi] + bb;
}

extern "C" void kernel_launch(void* const* d_in, const int* in_sizes, int n_in,
                              void* d_out, int out_size, void* d_ws, size_t ws_size,
                              hipStream_t stream){
  const float* h_batch = (const float*)d_in[0];
  const int*   seq_lens= (const int*)d_in[1];
  const int*   labels  = (const int*)d_in[2];
  const float* attn_Ws = (const float*)d_in[3];
  const float* attn_Wh = (const float*)d_in[4];
  const float* attn_b  = (const float*)d_in[5];
  const float* attn_v  = (const float*)d_in[6];
  const float* W_sy    = (const float*)d_in[7];
  const float* b_sy    = (const float*)d_in[8];
  const float* W_gy    = (const float*)d_in[9];
  const float* b_gy    = (const float*)d_in[10];
  const float* W_yy    = (const float*)d_in[11];
  const float* b_yy    = (const float*)d_in[12];
  const float* E_yr    = (const float*)d_in[13];
  const float* W_sr    = (const float*)d_in[14];
  const float* b_sr    = (const float*)d_in[15];
  const float* W_gr    = (const float*)d_in[16];
  const float* b_gr    = (const float*)d_in[17];
  float* out = (float*)d_out;
  float* ws  = (float*)d_ws;

  float* hproj = ws + OFF_HPROJ;
  float* s     = ws + OFF_S;
  float* c     = ws + OFF_C;
  float* sws   = ws + OFF_SWS;
  float* dacc  = ws + OFF_DACC;
  float* racc  = ws + OFF_RACC;
  float* e     = ws + OFF_E;
  float* g     = ws + OFF_G;
  float* dect  = ws + OFF_DECT;

  k_init <<<512, 256, 0, stream>>>(ws);
  k_hproj<<<dim3(250, 8), 256, 0, stream>>>(h_batch, attn_Wh, attn_b, seq_lens, hproj);

  for (int l = 0; l < L_; ++l){
    k_sws   <<<dim3(2, 8),     256, 0, stream>>>(s, attn_Ws, sws);
    k_escore<<<4000,           256, 0, stream>>>(hproj, sws, attn_v, seq_lens, e);
    k_attng <<<dim3(32, 4),    256, 0, stream>>>(e, h_batch, seq_lens, g);
    k_recmm <<<dim3(10, 4, 2), 256, 0, stream>>>(s, g, W_sy, W_gy, W_sr, W_gr, dacc, racc);
    k_lstm  <<<32,             512, 0, stream>>>(dacc, racc, s, c, sws, dect, E_yr, labels,
                                                 b_sy, b_gy, b_sr, b_gr, l);
    k_vocab <<<dim3(40, 4),    256, 0, stream>>>(dect, W_yy, b_yy, out, l);
  }
}

// Round 3
// 19152.550 us; speedup vs baseline: 1.1235x; 1.1235x over previous
//
#include <hip/hip_runtime.h>
#include <hip/hip_cooperative_groups.h>
#include <cstdint>

namespace cg = cooperative_groups;

#define B_   32
#define T_   500
#define H_   512
#define ENC_ 1024
#define V_   10000
#define L_   100
#define H4_  2048
#define NB_  256
#define NT_  512

// workspace layout (float offsets), total 8371840 floats = 33.5 MB
#define OFF_HPROJ 0
#define OFF_S     8192000
#define OFF_C     8208384
#define OFF_DACC  8224768
#define OFF_RACC  8241152
#define OFF_G     8306688
#define OFF_E     8339456
#define OFF_DECT  8355456

__device__ __forceinline__ float ftanh(float x){
  float t = fminf(fmaxf(2.f*x, -30.f), 30.f);
  float e = __expf(t);
  return (e - 1.f) / (e + 1.f);
}
__device__ __forceinline__ float fsig(float x){
  float t = fminf(fmaxf(x, -30.f), 30.f);
  return 1.f / (1.f + __expf(-t));
}

// zero s, c, dacc, racc, g  (contiguous 147456 floats)
__global__ void k_init(float* __restrict__ ws){
  int i = blockIdx.x * 256 + threadIdx.x;
  if (i < 147456) ws[OFF_S + i] = 0.f;
}

// h_proj[m,n] = h_batch[m,:] @ Wh[:,n] + bias[n]; skips fully-masked 64-row tiles
__global__ void k_hproj(const float* __restrict__ A, const float* __restrict__ W,
                        const float* __restrict__ bias, const int* __restrict__ lens,
                        float* __restrict__ C){
  const int bm = blockIdx.x * 64;
  const int bn = blockIdx.y * 64;
  {
    int b0 = bm / T_, t0 = bm % T_;
    int b1 = (bm + 63) / T_;
    if (b0 == b1 && t0 >= lens[b0]) return;
  }
  __shared__ float As[64][33];
  __shared__ float Bs[32][68];
  const int tid = threadIdx.x;
  const int tx = tid & 15, ty = tid >> 4;
  float acc[4][4];
  #pragma unroll
  for (int i = 0; i < 4; ++i)
    #pragma unroll
    for (int j = 0; j < 4; ++j) acc[i][j] = 0.f;

  for (int k0 = 0; k0 < 1024; k0 += 32){
    for (int i = tid; i < 64*32; i += 256){
      int r = i >> 5, cc = i & 31;
      As[r][cc] = A[(size_t)(bm + r) * 1024 + k0 + cc];
    }
    for (int i = tid; i < 32*64; i += 256){
      int r = i >> 6, cc = i & 63;
      Bs[r][cc] = W[(size_t)(k0 + r) * 512 + bn + cc];
    }
    __syncthreads();
    #pragma unroll
    for (int kk = 0; kk < 32; ++kk){
      float a0 = As[ty*4+0][kk], a1 = As[ty*4+1][kk];
      float a2 = As[ty*4+2][kk], a3 = As[ty*4+3][kk];
      float4 b4 = *(const float4*)&Bs[kk][tx*4];
      acc[0][0] += a0*b4.x; acc[0][1] += a0*b4.y; acc[0][2] += a0*b4.z; acc[0][3] += a0*b4.w;
      acc[1][0] += a1*b4.x; acc[1][1] += a1*b4.y; acc[1][2] += a1*b4.z; acc[1][3] += a1*b4.w;
      acc[2][0] += a2*b4.x; acc[2][1] += a2*b4.y; acc[2][2] += a2*b4.z; acc[2][3] += a2*b4.w;
      acc[3][0] += a3*b4.x; acc[3][1] += a3*b4.y; acc[3][2] += a3*b4.z; acc[3][3] += a3*b4.w;
    }
    __syncthreads();
  }
  #pragma unroll
  for (int i = 0; i < 4; ++i){
    int m = bm + ty*4 + i;
    float4 o;
    o.x = acc[i][0] + bias[bn + tx*4 + 0];
    o.y = acc[i][1] + bias[bn + tx*4 + 1];
    o.z = acc[i][2] + bias[bn + tx*4 + 2];
    o.w = acc[i][3] + bias[bn + tx*4 + 3];
    *(float4*)&C[(size_t)m * 512 + bn + tx*4] = o;
  }
}

// Persistent cooperative kernel: the whole 100-step decode loop.
// 256 blocks x 512 threads = 1 block/CU (cooperative co-residency guaranteed).
__global__ __launch_bounds__(512, 2) void k_persist(
    const float* __restrict__ hb,  const int* __restrict__ lens,
    const int* __restrict__ labels,
    const float* __restrict__ Ws,  const float* __restrict__ av,
    const float* __restrict__ Wsy, const float* __restrict__ bsy,
    const float* __restrict__ Wgy, const float* __restrict__ bgy,
    const float* __restrict__ Wyy, const float* __restrict__ byy,
    const float* __restrict__ Eyr, const float* __restrict__ Wsr,
    const float* __restrict__ bsr, const float* __restrict__ Wgr,
    const float* __restrict__ bgr,
    float* __restrict__ out, float* __restrict__ ws)
{
  cg::grid_group grid = cg::this_grid();
  const int blk = blockIdx.x;
  const int tid = threadIdx.x;
  __shared__ __align__(16) float smem[4096];   // 16 KB

  for (int l = 0; l <= L_; ++l){
    // ============ P0: vocab(l-1) [blk 0..79]  ||  e-scores(l) [blk 80..239] ============
    if (blk < 80){
      if (l > 0){
        // out[b, l-1, v] = dect[b,:] @ Wyy[:,v] + byy[v]; full K, direct store
        const int vb   = blk >> 2;          // 0..19 (512 v each)
        const int brow = (blk & 3) * 8;     // 8 batch rows
        const int v    = vb*512 + tid;
        const int vc   = (v < V_) ? v : (V_-1);
        const float* dect = ws + OFF_DECT;
        for (int i = tid; i < 4096; i += NT_){
          int k = i >> 3, bi = i & 7;
          smem[i] = dect[(brow+bi)*H_ + k];   // layout [k][bi]
        }
        __syncthreads();
        float acc[8];
        #pragma unroll
        for (int bi = 0; bi < 8; ++bi) acc[bi] = 0.f;
        const float* wp = Wyy + vc;
        float w0[8], w1[8];
        #pragma unroll
        for (int j = 0; j < 8; ++j) w0[j] = wp[(size_t)j * V_];
        for (int kk = 0; kk < 512; kk += 8){
          if (kk + 8 < 512){
            #pragma unroll
            for (int j = 0; j < 8; ++j) w1[j] = wp[(size_t)(kk+8+j) * V_];
          }
          #pragma unroll
          for (int j = 0; j < 8; ++j){
            const float* ap = &smem[(kk+j)*8];
            float4 a0 = *(const float4*)(ap);
            float4 a1 = *(const float4*)(ap+4);
            float wj = w0[j];
            acc[0] += a0.x*wj; acc[1] += a0.y*wj; acc[2] += a0.z*wj; acc[3] += a0.w*wj;
            acc[4] += a1.x*wj; acc[5] += a1.y*wj; acc[6] += a1.z*wj; acc[7] += a1.w*wj;
          }
          #pragma unroll
          for (int j = 0; j < 8; ++j) w0[j] = w1[j];
        }
        if (v < V_){
          const float bb = byy[v];
          const int lv = l - 1;
          #pragma unroll
          for (int bi = 0; bi < 8; ++bi)
            out[((size_t)(brow+bi)*L_ + lv)*V_ + v] = acc[bi] + bb;
        }
      }
    } else if (blk < 240){
      if (l < L_){
        // per-block redundant sws[b,:] = s[b,:]@Ws (L2-resident Ws), then e rows
        const int u  = blk - 80;
        const int b  = u / 5;
        const int ch = u % 5;
        const int len = lens[b];
        const int t0 = ch*100;
        const int t1 = min(t0 + 100, len);
        float* ssm = smem;          // s[b,:]   512
        float* wsm = smem + 512;    // sws[b,:] 512
        ssm[tid] = ws[OFF_S + b*H_ + tid];
        __syncthreads();
        {
          const float* wp = Ws + tid;
          float acc = 0.f;
          float w0[8], w1[8];
          #pragma unroll
          for (int j = 0; j < 8; ++j) w0[j] = wp[(size_t)j * H_];
          for (int kk = 0; kk < 512; kk += 8){
            if (kk + 8 < 512){
              #pragma unroll
              for (int j = 0; j < 8; ++j) w1[j] = wp[(size_t)(kk+8+j) * H_];
            }
            #pragma unroll
            for (int j = 0; j < 8; ++j) acc += ssm[kk+j] * w0[j];
            #pragma unroll
            for (int j = 0; j < 8; ++j) w0[j] = w1[j];
          }
          wsm[tid] = acc;
        }
        __syncthreads();
        const int wid = tid >> 6, lane = tid & 63;
        float* e = ws + OFF_E;
        for (int t = t0 + wid; t < t1; t += 8){
          const float* hp = ws + OFF_HPROJ + (size_t)(b*T_ + t) * H_;
          float sum = 0.f;
          #pragma unroll
          for (int it = 0; it < 2; ++it){
            int h = it*256 + lane*4;
            float4 a  = *(const float4*)&hp[h];
            float4 sw = *(const float4*)&wsm[h];
            float4 vv = *(const float4*)&av[h];
            sum += vv.x * ftanh(a.x + sw.x);
            sum += vv.y * ftanh(a.y + sw.y);
            sum += vv.z * ftanh(a.z + sw.z);
            sum += vv.w * ftanh(a.w + sw.w);
          }
          #pragma unroll
          for (int off = 32; off > 0; off >>= 1) sum += __shfl_xor(sum, off, 64);
          if (lane == 0) e[b*T_ + t] = sum;
        }
      }
    }
    if (l == L_) break;            // uniform across all blocks
    grid.sync();

    // ============ P1: softmax + partial g (all 256 blocks) ============
    {
      const int tq   = blk >> 6;     // 0..3  t-quarter
      const int r    = blk & 63;
      const int b    = r >> 1;       // 0..31
      const int half = r & 1;        // ENC half
      const int len  = lens[b];
      float* sc  = smem;
      float* red = smem + 512;
      const float* e = ws + OFF_E;
      float val = (tid < len) ? e[b*T_ + tid] : -1e30f;
      sc[tid]  = val;
      red[tid] = val;
      __syncthreads();
      for (int st = 256; st > 0; st >>= 1){
        if (tid < st) red[tid] = fmaxf(red[tid], red[tid+st]);
        __syncthreads();
      }
      const float mx = red[0];
      __syncthreads();
      float ex = (tid < len) ? __expf(val - mx) : 0.f;
      sc[tid]  = ex;
      red[tid] = ex;
      __syncthreads();
      for (int st = 256; st > 0; st >>= 1){
        if (tid < st) red[tid] += red[tid+st];
        __syncthreads();
      }
      const float inv = 1.f / red[0];
      const int clen = (len + 3) >> 2;
      const int t0 = tq*clen, t1 = min(t0 + clen, len);
      const int col = half*512 + tid;
      const float* hp = hb + (size_t)b*T_*ENC_ + col;
      float acc = 0.f;
      #pragma unroll 4
      for (int t = t0; t < t1; ++t) acc += sc[t] * hp[(size_t)t * ENC_];
      if (t1 > t0) atomicAdd(&ws[OFF_G + b*ENC_ + col], acc * inv);
    }
    grid.sync();

    // ============ P2: dec/rec matmuls into dacc/racc [blk 0..159] ============
    if (blk < 160){
      const int cb   = blk >> 5;          // 0..4 (512 cols)
      const int r2   = blk & 31;
      const int brow = (r2 >> 3) * 8;     // 8 batch rows
      const int k0   = (r2 & 7) * 192;    // k-chunk
      for (int i = tid; i < 1536; i += NT_){
        int k = i >> 3, bi = i & 7;
        int kk = k0 + k, row = brow + bi;
        smem[i] = (kk < H_) ? ws[OFF_S + row*H_ + kk]
                            : ws[OFF_G + row*ENC_ + (kk - H_)];
      }
      __syncthreads();
      const int col = cb*512 + tid;       // 0..2559
      const bool isdec = (col < H_);
      const int cr = col - H_;
      float acc[8];
      #pragma unroll
      for (int bi = 0; bi < 8; ++bi) acc[bi] = 0.f;
      float w0[8], w1[8];
      #pragma unroll
      for (int j = 0; j < 8; ++j){
        int k = k0 + j;
        w0[j] = isdec ? ((k < H_) ? Wsy[(size_t)k*H_ + col] : Wgy[(size_t)(k-H_)*H_ + col])
                      : ((k < H_) ? Wsr[(size_t)k*H4_ + cr] : Wgr[(size_t)(k-H_)*H4_ + cr]);
      }
      for (int kk = 0; kk < 192; kk += 8){
        if (kk + 8 < 192){
          #pragma unroll
          for (int j = 0; j < 8; ++j){
            int k = k0 + kk + 8 + j;
            w1[j] = isdec ? ((k < H_) ? Wsy[(size_t)k*H_ + col] : Wgy[(size_t)(k-H_)*H_ + col])
                          : ((k < H_) ? Wsr[(size_t)k*H4_ + cr] : Wgr[(size_t)(k-H_)*H4_ + cr]);
          }
        }
        #pragma unroll
        for (int j = 0; j < 8; ++j){
          const float* ap = &smem[(kk+j)*8];
          float4 a0 = *(const float4*)(ap);
          float4 a1 = *(const float4*)(ap+4);
          float wj = w0[j];
          acc[0] += a0.x*wj; acc[1] += a0.y*wj; acc[2] += a0.z*wj; acc[3] += a0.w*wj;
          acc[4] += a1.x*wj; acc[5] += a1.y*wj; acc[6] += a1.z*wj; acc[7] += a1.w*wj;
        }
        #pragma unroll
        for (int j = 0; j < 8; ++j) w0[j] = w1[j];
      }
      #pragma unroll
      for (int bi = 0; bi < 8; ++bi){
        int row = brow + bi;
        if (isdec) atomicAdd(&ws[OFF_DACC + row*H_  + col], acc[bi]);
        else       atomicAdd(&ws[OFF_RACC + row*H4_ + cr],  acc[bi]);
      }
    }
    grid.sync();

    // ============ P3: LSTM + dect [blk 0..31]; zero g [blk 32..63] ============
    if (blk < 32){
      const int b = blk;
      const int h = tid;
      const int lab = labels[b*L_ + l];
      const float* ey = Eyr + (size_t)lab * H4_;
      const int base = b*H4_;
      float ri = ws[OFF_RACC+base+h]       + bsr[h]       + bgr[h]       + ey[h];
      float rf = ws[OFF_RACC+base+512+h]   + bsr[512+h]   + bgr[512+h]   + ey[512+h];
      float rg = ws[OFF_RACC+base+1024+h]  + bsr[1024+h]  + bgr[1024+h]  + ey[1024+h];
      float ro = ws[OFF_RACC+base+1536+h]  + bsr[1536+h]  + bgr[1536+h]  + ey[1536+h];
      float cold = ws[OFF_C + b*H_ + h];
      float cn = fsig(rf)*cold + fsig(ri)*ftanh(rg);
      float sn = fsig(ro)*ftanh(cn);
      ws[OFF_C + b*H_ + h] = cn;
      ws[OFF_S + b*H_ + h] = sn;
      float d = ws[OFF_DACC + b*H_ + h] + bsy[h] + bgy[h];
      ws[OFF_DECT + b*H_ + h] = ftanh(d);
      ws[OFF_RACC+base+h] = 0.f;
      ws[OFF_RACC+base+512+h] = 0.f;
      ws[OFF_RACC+base+1024+h] = 0.f;
      ws[OFF_RACC+base+1536+h] = 0.f;
      ws[OFF_DACC + b*H_ + h] = 0.f;
    } else if (blk < 64){
      int i = (blk - 32)*NT_ + tid;
      ws[OFF_G + i] = 0.f;
      ws[OFF_G + 16384 + i] = 0.f;
    }
    grid.sync();
  }
}

extern "C" void kernel_launch(void* const* d_in, const int* in_sizes, int n_in,
                              void* d_out, int out_size, void* d_ws, size_t ws_size,
                              hipStream_t stream){
  const float* h_batch = (const float*)d_in[0];
  const int*   seq_lens= (const int*)d_in[1];
  const int*   labels  = (const int*)d_in[2];
  const float* attn_Ws = (const float*)d_in[3];
  const float* attn_Wh = (const float*)d_in[4];
  const float* attn_b  = (const float*)d_in[5];
  const float* attn_v  = (const float*)d_in[6];
  const float* W_sy    = (const float*)d_in[7];
  const float* b_sy    = (const float*)d_in[8];
  const float* W_gy    = (const float*)d_in[9];
  const float* b_gy    = (const float*)d_in[10];
  const float* W_yy    = (const float*)d_in[11];
  const float* b_yy    = (const float*)d_in[12];
  const float* E_yr    = (const float*)d_in[13];
  const float* W_sr    = (const float*)d_in[14];
  const float* b_sr    = (const float*)d_in[15];
  const float* W_gr    = (const float*)d_in[16];
  const float* b_gr    = (const float*)d_in[17];
  float* out = (float*)d_out;
  float* ws  = (float*)d_ws;

  k_init <<<576, 256, 0, stream>>>(ws);
  k_hproj<<<dim3(250, 8), 256, 0, stream>>>(h_batch, attn_Wh, attn_b, seq_lens,
                                            ws + OFF_HPROJ);

  void* kargs[] = {
    (void*)&h_batch, (void*)&seq_lens, (void*)&labels,
    (void*)&attn_Ws, (void*)&attn_v,
    (void*)&W_sy, (void*)&b_sy, (void*)&W_gy, (void*)&b_gy,
    (void*)&W_yy, (void*)&b_yy,
    (void*)&E_yr, (void*)&W_sr, (void*)&b_sr, (void*)&W_gr, (void*)&b_gr,
    (void*)&out, (void*)&ws
  };
  hipLaunchCooperativeKernel((void*)k_persist, dim3(NB_), dim3(NT_), kargs, 0, stream);
}

// Round 4
// 12493.112 us; speedup vs baseline: 1.7223x; 1.5330x over previous
//
#include <hip/hip_runtime.h>
#include <cstdint>

#define B_   32
#define T_   500
#define H_   512
#define ENC_ 1024
#define V_   10000
#define L_   100
#define H4_  2048
#define NB_  256
#define NT_  512

// workspace layout (float offsets)
#define OFF_HPROJ 0
#define OFF_S     8192000
#define OFF_C     8208384
#define OFF_DACC  8224768
#define OFF_RACC  8241152
#define OFF_G     8306688
#define OFF_E     8339456
#define OFF_DECT  8355456
#define OFF_BAR   8371840   // 17 uint32 barrier counters

__device__ __forceinline__ float ftanh(float x){
  float t = fminf(fmaxf(2.f*x, -30.f), 30.f);
  float e = __expf(t);
  return (e - 1.f) / (e + 1.f);
}
__device__ __forceinline__ float fsig(float x){
  float t = fminf(fmaxf(x, -30.f), 30.f);
  return 1.f / (1.f + __expf(-t));
}

// agent-scope (device) relaxed atomic load/store: bypass L1/L2, hit coherent L3.
__device__ __forceinline__ float gload(const float* p){
  return __hip_atomic_load((float*)p, __ATOMIC_RELAXED, __HIP_MEMORY_SCOPE_AGENT);
}
__device__ __forceinline__ void gstore(float* p, float v){
  __hip_atomic_store(p, v, __ATOMIC_RELAXED, __HIP_MEMORY_SCOPE_AGENT);
}

// Two-level grid barrier, monotonic counters, no cache-maintenance fences.
// bars[0] = root, bars[1..16] = 16 group counters (16 blocks/group).
__device__ __forceinline__ void gridbar(unsigned* bars, unsigned it){
  asm volatile("s_waitcnt vmcnt(0) lgkmcnt(0)" ::: "memory");
  __syncthreads();
  if (threadIdx.x == 0){
    unsigned* gc = bars + 1 + (blockIdx.x & 15);
    unsigned old = __hip_atomic_fetch_add(gc, 1u, __ATOMIC_RELAXED, __HIP_MEMORY_SCOPE_AGENT);
    if (old == it*16u + 15u)
      __hip_atomic_fetch_add(bars, 1u, __ATOMIC_RELAXED, __HIP_MEMORY_SCOPE_AGENT);
    while (__hip_atomic_load(bars, __ATOMIC_RELAXED, __HIP_MEMORY_SCOPE_AGENT) < (it+1u)*16u)
      __builtin_amdgcn_s_sleep(2);
  }
  __syncthreads();
  asm volatile("" ::: "memory");
}

// zero s, c, dacc, racc, g, e, dect, barrier counters
__global__ void k_init(float* __restrict__ ws){
  int i = blockIdx.x * 256 + threadIdx.x;
  if (i < 180224) ws[OFF_S + i] = 0.f;
}

// h_proj[m,n] = h_batch[m,:] @ Wh[:,n] + bias[n]; skips fully-masked 64-row tiles
__global__ void k_hproj(const float* __restrict__ A, const float* __restrict__ W,
                        const float* __restrict__ bias, const int* __restrict__ lens,
                        float* __restrict__ C){
  const int bm = blockIdx.x * 64;
  const int bn = blockIdx.y * 64;
  {
    int b0 = bm / T_, t0 = bm % T_;
    int b1 = (bm + 63) / T_;
    if (b0 == b1 && t0 >= lens[b0]) return;
  }
  __shared__ float As[64][33];
  __shared__ float Bs[32][68];
  const int tid = threadIdx.x;
  const int tx = tid & 15, ty = tid >> 4;
  float acc[4][4];
  #pragma unroll
  for (int i = 0; i < 4; ++i)
    #pragma unroll
    for (int j = 0; j < 4; ++j) acc[i][j] = 0.f;

  for (int k0 = 0; k0 < 1024; k0 += 32){
    for (int i = tid; i < 64*32; i += 256){
      int r = i >> 5, cc = i & 31;
      As[r][cc] = A[(size_t)(bm + r) * 1024 + k0 + cc];
    }
    for (int i = tid; i < 32*64; i += 256){
      int r = i >> 6, cc = i & 63;
      Bs[r][cc] = W[(size_t)(k0 + r) * 512 + bn + cc];
    }
    __syncthreads();
    #pragma unroll
    for (int kk = 0; kk < 32; ++kk){
      float a0 = As[ty*4+0][kk], a1 = As[ty*4+1][kk];
      float a2 = As[ty*4+2][kk], a3 = As[ty*4+3][kk];
      float4 b4 = *(const float4*)&Bs[kk][tx*4];
      acc[0][0] += a0*b4.x; acc[0][1] += a0*b4.y; acc[0][2] += a0*b4.z; acc[0][3] += a0*b4.w;
      acc[1][0] += a1*b4.x; acc[1][1] += a1*b4.y; acc[1][2] += a1*b4.z; acc[1][3] += a1*b4.w;
      acc[2][0] += a2*b4.x; acc[2][1] += a2*b4.y; acc[2][2] += a2*b4.z; acc[2][3] += a2*b4.w;
      acc[3][0] += a3*b4.x; acc[3][1] += a3*b4.y; acc[3][2] += a3*b4.z; acc[3][3] += a3*b4.w;
    }
    __syncthreads();
  }
  #pragma unroll
  for (int i = 0; i < 4; ++i){
    int m = bm + ty*4 + i;
    float4 o;
    o.x = acc[i][0] + bias[bn + tx*4 + 0];
    o.y = acc[i][1] + bias[bn + tx*4 + 1];
    o.z = acc[i][2] + bias[bn + tx*4 + 2];
    o.w = acc[i][3] + bias[bn + tx*4 + 3];
    *(float4*)&C[(size_t)m * 512 + bn + tx*4] = o;
  }
}

// Persistent cooperative kernel: the whole 100-step decode loop.
__global__ __launch_bounds__(512, 2) void k_persist(
    const float* __restrict__ hb,  const int* __restrict__ lens,
    const int* __restrict__ labels,
    const float* __restrict__ Ws,  const float* __restrict__ av,
    const float* __restrict__ Wsy, const float* __restrict__ bsy,
    const float* __restrict__ Wgy, const float* __restrict__ bgy,
    const float* __restrict__ Wyy, const float* __restrict__ byy,
    const float* __restrict__ Eyr, const float* __restrict__ Wsr,
    const float* __restrict__ bsr, const float* __restrict__ Wgr,
    const float* __restrict__ bgr,
    float* __restrict__ out, float* __restrict__ ws)
{
  const int blk = blockIdx.x;
  const int tid = threadIdx.x;
  unsigned* bars = (unsigned*)(ws + OFF_BAR);
  __shared__ __align__(16) float smem[4096];   // 16 KB

  for (int l = 0; l <= L_; ++l){
    // ============ P0: vocab(l-1) [blk 0..79]  ||  e-scores(l) [blk 80..239] ============
    if (blk < 80){
      if (l > 0){
        const int vb   = blk >> 2;          // 0..19 (512 v each)
        const int brow = (blk & 3) * 8;     // 8 batch rows
        const int v    = vb*512 + tid;
        const int vc   = (v < V_) ? v : (V_-1);
        const float* dect = ws + OFF_DECT;
        for (int i = tid; i < 4096; i += NT_){
          int k = i >> 3, bi = i & 7;
          smem[i] = gload(&dect[(brow+bi)*H_ + k]);   // layout [k][bi]
        }
        __syncthreads();
        float acc[8];
        #pragma unroll
        for (int bi = 0; bi < 8; ++bi) acc[bi] = 0.f;
        const float* wp = Wyy + vc;
        float w0[8], w1[8];
        #pragma unroll
        for (int j = 0; j < 8; ++j) w0[j] = wp[(size_t)j * V_];
        for (int kk = 0; kk < 512; kk += 8){
          if (kk + 8 < 512){
            #pragma unroll
            for (int j = 0; j < 8; ++j) w1[j] = wp[(size_t)(kk+8+j) * V_];
          }
          #pragma unroll
          for (int j = 0; j < 8; ++j){
            const float* ap = &smem[(kk+j)*8];
            float4 a0 = *(const float4*)(ap);
            float4 a1 = *(const float4*)(ap+4);
            float wj = w0[j];
            acc[0] += a0.x*wj; acc[1] += a0.y*wj; acc[2] += a0.z*wj; acc[3] += a0.w*wj;
            acc[4] += a1.x*wj; acc[5] += a1.y*wj; acc[6] += a1.z*wj; acc[7] += a1.w*wj;
          }
          #pragma unroll
          for (int j = 0; j < 8; ++j) w0[j] = w1[j];
        }
        if (v < V_){
          const float bb = byy[v];
          const int lv = l - 1;
          #pragma unroll
          for (int bi = 0; bi < 8; ++bi)
            out[((size_t)(brow+bi)*L_ + lv)*V_ + v] = acc[bi] + bb;
        }
        __syncthreads();
      }
    } else if (blk < 240){
      if (l < L_){
        const int u  = blk - 80;
        const int b  = u / 5;
        const int ch = u % 5;
        const int len = lens[b];
        const int t0 = ch*100;
        const int t1 = min(t0 + 100, len);
        float* ssm = smem;          // s[b,:]   512
        float* wsm = smem + 512;    // sws[b,:] 512
        ssm[tid] = gload(&ws[OFF_S + b*H_ + tid]);
        __syncthreads();
        {
          const float* wp = Ws + tid;
          float acc = 0.f;
          float w0[8], w1[8];
          #pragma unroll
          for (int j = 0; j < 8; ++j) w0[j] = wp[(size_t)j * H_];
          for (int kk = 0; kk < 512; kk += 8){
            if (kk + 8 < 512){
              #pragma unroll
              for (int j = 0; j < 8; ++j) w1[j] = wp[(size_t)(kk+8+j) * H_];
            }
            #pragma unroll
            for (int j = 0; j < 8; ++j) acc += ssm[kk+j] * w0[j];
            #pragma unroll
            for (int j = 0; j < 8; ++j) w0[j] = w1[j];
          }
          wsm[tid] = acc;
        }
        __syncthreads();
        const int wid = tid >> 6, lane = tid & 63;
        float* e = ws + OFF_E;
        for (int t = t0 + wid; t < t1; t += 8){
          const float* hp = ws + OFF_HPROJ + (size_t)(b*T_ + t) * H_;
          float sum = 0.f;
          #pragma unroll
          for (int it = 0; it < 2; ++it){
            int h = it*256 + lane*4;
            float4 a  = *(const float4*)&hp[h];
            float4 sw = *(const float4*)&wsm[h];
            float4 vv = *(const float4*)&av[h];
            sum += vv.x * ftanh(a.x + sw.x);
            sum += vv.y * ftanh(a.y + sw.y);
            sum += vv.z * ftanh(a.z + sw.z);
            sum += vv.w * ftanh(a.w + sw.w);
          }
          #pragma unroll
          for (int off = 32; off > 0; off >>= 1) sum += __shfl_xor(sum, off, 64);
          if (lane == 0) gstore(&e[b*T_ + t], sum);
        }
      }
    }
    if (l == L_) break;            // uniform across all blocks
    gridbar(bars, (unsigned)(l*4 + 0));

    // ============ P1: softmax + partial g (all 256 blocks) ============
    {
      const int tq   = blk >> 6;     // 0..3  t-quarter
      const int r    = blk & 63;
      const int b    = r >> 1;       // 0..31
      const int half = r & 1;        // ENC half
      const int len  = lens[b];
      float* sc  = smem;
      float* red = smem + 512;
      const float* e = ws + OFF_E;
      float val = (tid < len) ? gload(&e[b*T_ + tid]) : -1e30f;
      sc[tid]  = val;
      red[tid] = val;
      __syncthreads();
      for (int st = 256; st > 0; st >>= 1){
        if (tid < st) red[tid] = fmaxf(red[tid], red[tid+st]);
        __syncthreads();
      }
      const float mx = red[0];
      __syncthreads();
      float ex = (tid < len) ? __expf(val - mx) : 0.f;
      sc[tid]  = ex;
      red[tid] = ex;
      __syncthreads();
      for (int st = 256; st > 0; st >>= 1){
        if (tid < st) red[tid] += red[tid+st];
        __syncthreads();
      }
      const float inv = 1.f / red[0];
      const int clen = (len + 3) >> 2;
      const int t0 = tq*clen, t1 = min(t0 + clen, len);
      const int col = half*512 + tid;
      const float* hp = hb + (size_t)b*T_*ENC_ + col;
      float acc = 0.f;
      #pragma unroll 4
      for (int t = t0; t < t1; ++t) acc += sc[t] * hp[(size_t)t * ENC_];
      if (t1 > t0) atomicAdd(&ws[OFF_G + b*ENC_ + col], acc * inv);
    }
    gridbar(bars, (unsigned)(l*4 + 1));

    // ============ P2: dec/rec matmuls into dacc/racc [blk 0..159] ============
    if (blk < 160){
      const int cb   = blk >> 5;          // 0..4 (512 cols)
      const int r2   = blk & 31;
      const int brow = (r2 >> 3) * 8;     // 8 batch rows
      const int k0   = (r2 & 7) * 192;    // k-chunk
      for (int i = tid; i < 1536; i += NT_){
        int k = i >> 3, bi = i & 7;
        int kk = k0 + k, row = brow + bi;
        smem[i] = (kk < H_) ? gload(&ws[OFF_S + row*H_ + kk])
                            : gload(&ws[OFF_G + row*ENC_ + (kk - H_)]);
      }
      __syncthreads();
      const int col = cb*512 + tid;       // 0..2559
      const bool isdec = (col < H_);
      const int cr = col - H_;
      float acc[8];
      #pragma unroll
      for (int bi = 0; bi < 8; ++bi) acc[bi] = 0.f;
      float w0[8], w1[8];
      #pragma unroll
      for (int j = 0; j < 8; ++j){
        int k = k0 + j;
        w0[j] = isdec ? ((k < H_) ? Wsy[(size_t)k*H_ + col] : Wgy[(size_t)(k-H_)*H_ + col])
                      : ((k < H_) ? Wsr[(size_t)k*H4_ + cr] : Wgr[(size_t)(k-H_)*H4_ + cr]);
      }
      for (int kk = 0; kk < 192; kk += 8){
        if (kk + 8 < 192){
          #pragma unroll
          for (int j = 0; j < 8; ++j){
            int k = k0 + kk + 8 + j;
            w1[j] = isdec ? ((k < H_) ? Wsy[(size_t)k*H_ + col] : Wgy[(size_t)(k-H_)*H_ + col])
                          : ((k < H_) ? Wsr[(size_t)k*H4_ + cr] : Wgr[(size_t)(k-H_)*H4_ + cr]);
          }
        }
        #pragma unroll
        for (int j = 0; j < 8; ++j){
          const float* ap = &smem[(kk+j)*8];
          float4 a0 = *(const float4*)(ap);
          float4 a1 = *(const float4*)(ap+4);
          float wj = w0[j];
          acc[0] += a0.x*wj; acc[1] += a0.y*wj; acc[2] += a0.z*wj; acc[3] += a0.w*wj;
          acc[4] += a1.x*wj; acc[5] += a1.y*wj; acc[6] += a1.z*wj; acc[7] += a1.w*wj;
        }
        #pragma unroll
        for (int j = 0; j < 8; ++j) w0[j] = w1[j];
      }
      #pragma unroll
      for (int bi = 0; bi < 8; ++bi){
        int row = brow + bi;
        if (isdec) atomicAdd(&ws[OFF_DACC + row*H_  + col], acc[bi]);
        else       atomicAdd(&ws[OFF_RACC + row*H4_ + cr],  acc[bi]);
      }
      __syncthreads();
    }
    gridbar(bars, (unsigned)(l*4 + 2));

    // ============ P3: LSTM + dect [blk 0..31]; zero g [blk 32..63] ============
    if (blk < 32){
      const int b = blk;
      const int h = tid;
      const int lab = labels[b*L_ + l];
      const float* ey = Eyr + (size_t)lab * H4_;
      const int base = b*H4_;
      float ri = gload(&ws[OFF_RACC+base+h])      + bsr[h]       + bgr[h]       + ey[h];
      float rf = gload(&ws[OFF_RACC+base+512+h])  + bsr[512+h]   + bgr[512+h]   + ey[512+h];
      float rg = gload(&ws[OFF_RACC+base+1024+h]) + bsr[1024+h]  + bgr[1024+h]  + ey[1024+h];
      float ro = gload(&ws[OFF_RACC+base+1536+h]) + bsr[1536+h]  + bgr[1536+h]  + ey[1536+h];
      float cold = ws[OFF_C + b*H_ + h];          // c is block-private (same CU every step)
      float cn = fsig(rf)*cold + fsig(ri)*ftanh(rg);
      float sn = fsig(ro)*ftanh(cn);
      ws[OFF_C + b*H_ + h] = cn;
      gstore(&ws[OFF_S + b*H_ + h], sn);
      float d = gload(&ws[OFF_DACC + b*H_ + h]) + bsy[h] + bgy[h];
      gstore(&ws[OFF_DECT + b*H_ + h], ftanh(d));
      gstore(&ws[OFF_RACC+base+h], 0.f);
      gstore(&ws[OFF_RACC+base+512+h], 0.f);
      gstore(&ws[OFF_RACC+base+1024+h], 0.f);
      gstore(&ws[OFF_RACC+base+1536+h], 0.f);
      gstore(&ws[OFF_DACC + b*H_ + h], 0.f);
    } else if (blk < 64){
      int i = (blk - 32)*NT_ + tid;
      gstore(&ws[OFF_G + i], 0.f);
      gstore(&ws[OFF_G + 16384 + i], 0.f);
    }
    gridbar(bars, (unsigned)(l*4 + 3));
  }
}

extern "C" void kernel_launch(void* const* d_in, const int* in_sizes, int n_in,
                              void* d_out, int out_size, void* d_ws, size_t ws_size,
                              hipStream_t stream){
  const float* h_batch = (const float*)d_in[0];
  const int*   seq_lens= (const int*)d_in[1];
  const int*   labels  = (const int*)d_in[2];
  const float* attn_Ws = (const float*)d_in[3];
  const float* attn_Wh = (const float*)d_in[4];
  const float* attn_b  = (const float*)d_in[5];
  const float* attn_v  = (const float*)d_in[6];
  const float* W_sy    = (const float*)d_in[7];
  const float* b_sy    = (const float*)d_in[8];
  const float* W_gy    = (const float*)d_in[9];
  const float* b_gy    = (const float*)d_in[10];
  const float* W_yy    = (const float*)d_in[11];
  const float* b_yy    = (const float*)d_in[12];
  const float* E_yr    = (const float*)d_in[13];
  const float* W_sr    = (const float*)d_in[14];
  const float* b_sr    = (const float*)d_in[15];
  const float* W_gr    = (const float*)d_in[16];
  const float* b_gr    = (const float*)d_in[17];
  float* out = (float*)d_out;
  float* ws  = (float*)d_ws;

  k_init <<<704, 256, 0, stream>>>(ws);
  k_hproj<<<dim3(250, 8), 256, 0, stream>>>(h_batch, attn_Wh, attn_b, seq_lens,
                                            ws + OFF_HPROJ);

  void* kargs[] = {
    (void*)&h_batch, (void*)&seq_lens, (void*)&labels,
    (void*)&attn_Ws, (void*)&attn_v,
    (void*)&W_sy, (void*)&b_sy, (void*)&W_gy, (void*)&b_gy,
    (void*)&W_yy, (void*)&b_yy,
    (void*)&E_yr, (void*)&W_sr, (void*)&b_sr, (void*)&W_gr, (void*)&b_gr,
    (void*)&out, (void*)&ws
  };
  hipLaunchCooperativeKernel((void*)k_persist, dim3(NB_), dim3(NT_), kargs, 0, stream);
}